// Round 4
// baseline (212.805 us; speedup 1.0000x reference)
//
#include <hip/hip_runtime.h>
#include <math.h>

// Problem constants (fixed by the reference harness).
constexpr int B = 16;
constexpr int N = 4096;
constexpr int K = 128;

constexpr int ROWS_PER_BLOCK = 128;   // 128 rows x 128 K = 16384 elems/block
constexpr int THREADS = 512;          // 8 waves
constexpr int WAVES   = THREADS / 64;
constexpr int EPC     = THREADS * 4;                       // 2048 elems/chunk
constexpr int CHUNKS  = (ROWS_PER_BLOCK * K) / EPC;        // 8
constexpr int DEPTH   = 2;            // double-buffered LDS stage

constexpr int SLAB_B  = 5 * 1024;     // per-wave slot: nbr 1K | mask 1K | offs 3K

// R8: LDS-DMA pipeline. R5-R7 post-mortem: three structures, identical 61-63us,
// VGPR never exceeded 64 — the pre-RA scheduler sinks VGPR-destined prefetch
// loads to their uses regardless of source structure, so per-wave in-flight
// depth stayed ~1 chunk and every pipe idled (VALU 7%, HBM 26%, LDS 15%).
// Fix: global_load_lds staging (no VGPR dest -> nothing to sink) + inline-asm
// COUNTED s_waitcnt vmcnt(N) (proven to keep loads in flight across consumers
// by the 8-phase GEMM template, m218). Each wave's chunk slice is lane-linear
// -> per-wave private 5KB slab, NO barriers in the main loop, per-wave vmcnt
// pipeline only. Wait ledger (stores counted): N0=5, N1..6=6, N7=1.

typedef float fx4 __attribute__((ext_vector_type(4)));
typedef int   ix4 __attribute__((ext_vector_type(4)));

#define AS1(p) ((const __attribute__((address_space(1))) void*)(p))
#define AS3(p) ((__attribute__((address_space(3))) void*)(p))

struct Ctx {
    const int*   nbr;
    const float* mask;
    const float* offs;
    float*       out;
    size_t base;            // blockElemBase
    int    nbase, wv, lane;
    float  c00, c01, c02, c10, c11, c12, c20, c21, c22;
};

// Issue the 5 LDS-DMA loads for chunk CC into this wave's slab (slot CC&1).
// Global src is per-lane (base + lane*16); LDS dest is wave-uniform base and
// HW adds lane*16 — both sides lane-linear, matching consumption layout.
template<int CC>
__device__ __forceinline__ void stage_chunk(const Ctx& x, char* slabs) {
    constexpr int slot = CC & (DEPTH - 1);
    char* slab = slabs + slot * (WAVES * SLAB_B);
    const size_t slice = x.base + (size_t)CC * EPC + (size_t)x.wv * 256;
    const int*   gn = x.nbr  + slice     + x.lane * 4;   // 16B/lane
    const float* gm = x.mask + slice     + x.lane * 4;
    const float* go = x.offs + slice * 3 + x.lane * 4;   // 3KB slice, 3 instrs
    __builtin_amdgcn_global_load_lds(AS1(gn),       AS3(slab),        16, 0, 0);
    __builtin_amdgcn_global_load_lds(AS1(gm),       AS3(slab + 1024), 16, 0, 0);
    __builtin_amdgcn_global_load_lds(AS1(go),       AS3(slab + 2048), 16, 0, 0);
    __builtin_amdgcn_global_load_lds(AS1(go + 256), AS3(slab + 3072), 16, 0, 0);
    __builtin_amdgcn_global_load_lds(AS1(go + 512), AS3(slab + 4096), 16, 0, 0);
    __builtin_amdgcn_sched_barrier(0);   // pin issue order (vmcnt ledger)
}

template<int C>
__device__ __forceinline__ void chunk_body(const Ctx& x, const fx4* spos,
                                           char* slabs) {
    constexpr int slot = C & (DEPTH - 1);
    // Outstanding after chunk C completes: C==0 -> chunk1's 5 DMAs;
    // steady   -> prev iter's store + 5 refill = 6;  C==7 -> iter6 store = 1.
    constexpr int NW = (C == 0) ? 5 : ((C == CHUNKS - 1) ? 1 : 6);
    asm volatile("s_waitcnt vmcnt(%0)" :: "n"(NW) : "memory");
    __builtin_amdgcn_sched_barrier(0);   // rule #18: no hoisting past the wait

    const char* slab = slabs + slot * (WAVES * SLAB_B);
    const ix4 jj = *(const ix4*)(slab + x.lane * 16);
    const fx4 mm = *(const fx4*)(slab + 1024 + x.lane * 16);
    const char* ob = slab + 2048 + x.lane * 48;          // 2-way alias: free
    const fx4 o0 = *(const fx4*)(ob);
    const fx4 o1 = *(const fx4*)(ob + 16);
    const fx4 o2 = *(const fx4*)(ob + 32);

    const int n  = x.nbase + C * (EPC / K) + x.wv * 2 + (x.lane >> 5);
    const fx4 pi = spos[n];

    const float ox[4] = {o0.x, o0.w, o1.z, o2.y};
    const float oy[4] = {o0.y, o1.x, o1.w, o2.z};
    const float oz[4] = {o0.z, o1.y, o2.x, o2.w};
    const int   j [4] = {jj.x, jj.y, jj.z, jj.w};
    const float m [4] = {mm.x, mm.y, mm.z, mm.w};

    float res[4];
#pragma unroll
    for (int i = 0; i < 4; ++i) {
        const fx4 pj = spos[j[i]];                        // one ds_read_b128
        const float dx = (pj.x - pi.x) + ox[i]*x.c00 + oy[i]*x.c10 + oz[i]*x.c20;
        const float dy = (pj.y - pi.y) + ox[i]*x.c01 + oy[i]*x.c11 + oz[i]*x.c21;
        const float dz = (pj.z - pi.z) + ox[i]*x.c02 + oy[i]*x.c12 + oz[i]*x.c22;
        const float sq = dx*dx + dy*dy + dz*dz;
        res[i] = (m[i] > 0.0f) ? __builtin_amdgcn_sqrtf(sq) : 0.0f;
    }
    const fx4 r = {res[0], res[1], res[2], res[3]};
    const size_t e0 = x.base + (size_t)C * EPC + (size_t)x.wv * 256
                      + (size_t)x.lane * 4;
    __builtin_nontemporal_store(r, (fx4*)(x.out + e0));

    if constexpr (C + DEPTH < CHUNKS) {
        // Slot (C&1) was just read; drain our ds_reads before the DMA
        // overwrites it, then refill chunk C+2 into the same slot.
        asm volatile("s_waitcnt lgkmcnt(0)" ::: "memory");
        __builtin_amdgcn_sched_barrier(0);
        stage_chunk<C + DEPTH>(x, slabs);
    }
}

template<int C>
__device__ __forceinline__ void run_chunks(const Ctx& x, const fx4* spos,
                                           char* slabs) {
    chunk_body<C>(x, spos, slabs);
    if constexpr (C + 1 < CHUNKS) run_chunks<C + 1>(x, spos, slabs);
}

__global__ __launch_bounds__(THREADS)
void pairwise_dist_dma(const float* __restrict__ pos,
                       const int*   __restrict__ nbr,
                       const float* __restrict__ mask,
                       const float* __restrict__ cell,
                       const float* __restrict__ offs,
                       float*       __restrict__ out) {
    __shared__ fx4 spos[N];                         // 64 KB
    __shared__ fx4 stagebuf[DEPTH][WAVES][SLAB_B / 16];  // 80 KB (16B aligned)

    const int tid   = threadIdx.x;
    const int wv    = tid >> 6;
    const int lane  = tid & 63;
    const int b     = blockIdx.x >> 5;              // 32 blocks per batch
    const int rblk  = blockIdx.x & 31;
    const int nbase = rblk * ROWS_PER_BLOCK;

    // Cell matrix: uniform per block -> scalar path (lgkmcnt, not vmcnt).
    const float* __restrict__ cb = cell + b * 9;
    const float c00 = cb[0], c01 = cb[1], c02 = cb[2];
    const float c10 = cb[3], c11 = cb[4], c12 = cb[5];
    const float c20 = cb[6], c21 = cb[7], c22 = cb[8];

    // Stage the batch's positions: 512 threads x 24 floats (6x float4 = 8
    // positions), repacked as 8 padded float4 atoms each. Coalesced.
    {
        const fx4* __restrict__ pb4 = (const fx4*)(pos + (size_t)b * N * 3);
        const fx4 r0 = pb4[tid * 6 + 0];
        const fx4 r1 = pb4[tid * 6 + 1];
        const fx4 r2 = pb4[tid * 6 + 2];
        const fx4 r3 = pb4[tid * 6 + 3];
        const fx4 r4 = pb4[tid * 6 + 4];
        const fx4 r5 = pb4[tid * 6 + 5];
        const int a0 = tid * 8;
        spos[a0 + 0] = (fx4){r0.x, r0.y, r0.z, 0.f};
        spos[a0 + 1] = (fx4){r0.w, r1.x, r1.y, 0.f};
        spos[a0 + 2] = (fx4){r1.z, r1.w, r2.x, 0.f};
        spos[a0 + 3] = (fx4){r2.y, r2.z, r2.w, 0.f};
        spos[a0 + 4] = (fx4){r3.x, r3.y, r3.z, 0.f};
        spos[a0 + 5] = (fx4){r3.w, r4.x, r4.y, 0.f};
        spos[a0 + 6] = (fx4){r4.z, r4.w, r5.x, 0.f};
        spos[a0 + 7] = (fx4){r5.y, r5.z, r5.w, 0.f};
    }

    Ctx x;
    x.nbr = nbr; x.mask = mask; x.offs = offs; x.out = out;
    x.base  = ((size_t)b * N + nbase) * K;
    x.nbase = nbase; x.wv = wv; x.lane = lane;
    x.c00 = c00; x.c01 = c01; x.c02 = c02;
    x.c10 = c10; x.c11 = c11; x.c12 = c12;
    x.c20 = c20; x.c21 = c21; x.c22 = c22;

    char* slabs = (char*)&stagebuf[0][wv][0];

    // Prologue: 2 chunks of LDS-DMA in flight before any wait.
    stage_chunk<0>(x, slabs);
    stage_chunk<1>(x, slabs);

    // Raw barrier for spos visibility (does NOT drain vmcnt — DMAs stay in
    // flight across it; only lgkm needs to complete for the ds_writes).
    asm volatile("s_waitcnt lgkmcnt(0)" ::: "memory");
    __builtin_amdgcn_s_barrier();
    __builtin_amdgcn_sched_barrier(0);

    run_chunks<0>(x, spos, slabs);
}

extern "C" void kernel_launch(void* const* d_in, const int* in_sizes, int n_in,
                              void* d_out, int out_size, void* d_ws, size_t ws_size,
                              hipStream_t stream) {
    const float* positions     = (const float*)d_in[0]; // [B,N,3]
    const int*   neighbors     = (const int*)  d_in[1]; // [B,N,K]
    const float* neighbor_mask = (const float*)d_in[2]; // [B,N,K]
    const float* cell          = (const float*)d_in[3]; // [B,3,3]
    const float* cell_offsets  = (const float*)d_in[4]; // [B,N,K,3]
    float*       out           = (float*)d_out;         // [B,N,K]

    const int blocks = B * (N / ROWS_PER_BLOCK);        // 16 * 32 = 512

    pairwise_dist_dma<<<blocks, THREADS, 0, stream>>>(
        positions, neighbors, neighbor_mask, cell, cell_offsets, out);
}

// Round 5
// 212.183 us; speedup vs baseline: 1.0029x; 1.0029x over previous
//
#include <hip/hip_runtime.h>
#include <math.h>

// Problem constants (fixed by the reference harness).
constexpr int B = 16;
constexpr int N = 4096;
constexpr int K = 128;

constexpr int ROWS_PER_BLOCK = 128;  // 128 rows x 128 K = 16384 elems/block
constexpr int THREADS = 1024;        // 16 elems/thread: 4 chunks of 4
constexpr int CHUNKS  = 4;
constexpr int WINDOW  = 2;           // rolling lookahead (compiler may sink)

typedef float fx4 __attribute__((ext_vector_type(4)));
typedef int   ix4 __attribute__((ext_vector_type(4)));

// R9: best-known structure (R4: 1024thr, 2 blocks/CU, 61-65us) with ALL
// nontemporal hints removed — the single remaining cache-policy variable.
// R4-R8 post-mortem: duration pinned at 61±2us across MLP depth 1->6 chunks
// (guaranteed via LDS-DMA in R8 — regressed), occupancy 9-55%, offs-NT
// on/off. VALUBusy 7% with all waves stalled = memory service rate is the
// binder (~2.75 TB/s read). NT on nbr/mask forces 67MB to always miss to
// HBM; NT on out bypasses L2 write absorption. Un-hinting maximizes L2/L3
// retention (FETCH already shows 85MB of 168 logical served off-HBM) and
// lets writes drain lazily. If flat: declare service-rate floor.

struct Chunk {
    ix4 jj;
    fx4 mm, o0, o1, o2;
};

__device__ __forceinline__ void load_chunk(Chunk& c,
                                           const int*   __restrict__ nbr,
                                           const float* __restrict__ mask,
                                           const float* __restrict__ offs,
                                           size_t e0) {
    c.jj = *(const ix4*)(nbr  + e0);
    c.mm = *(const fx4*)(mask + e0);
    const fx4* __restrict__ p = (const fx4*)(offs + e0 * 3);
    c.o0 = p[0];
    c.o1 = p[1];
    c.o2 = p[2];
}

__global__ __launch_bounds__(THREADS, 8)
void pairwise_dist_cached(const float* __restrict__ pos,
                          const int*   __restrict__ nbr,
                          const float* __restrict__ mask,
                          const float* __restrict__ cell,
                          const float* __restrict__ offs,
                          float*       __restrict__ out) {
    __shared__ fx4 spos[N];          // 64 KB

    const int tid   = threadIdx.x;
    const int b     = blockIdx.x >> 5;    // 32 blocks per batch
    const int rblk  = blockIdx.x & 31;
    const int nbase = rblk * ROWS_PER_BLOCK;

    // Stage the batch's full positions: 1024 threads x 12 consecutive floats
    // (3x float4), repacked as 4 padded float4 atoms each. Coalesced.
    {
        const fx4* __restrict__ pb4 = (const fx4*)(pos + (size_t)b * N * 3);
        const fx4 r0 = pb4[tid * 3 + 0];
        const fx4 r1 = pb4[tid * 3 + 1];
        const fx4 r2 = pb4[tid * 3 + 2];
        const int a0 = tid * 4;
        spos[a0 + 0] = (fx4){r0.x, r0.y, r0.z, 0.f};
        spos[a0 + 1] = (fx4){r0.w, r1.x, r1.y, 0.f};
        spos[a0 + 2] = (fx4){r1.z, r1.w, r2.x, 0.f};
        spos[a0 + 3] = (fx4){r2.y, r2.z, r2.w, 0.f};
    }

    // Cell matrix: uniform per block -> scalar (s_load) path.
    const float* __restrict__ cb = cell + b * 9;
    const float c00 = cb[0], c01 = cb[1], c02 = cb[2];
    const float c10 = cb[3], c11 = cb[4], c12 = cb[5];
    const float c20 = cb[6], c21 = cb[7], c22 = cb[8];

    const size_t blockElemBase = ((size_t)b * N + nbase) * K;

    // Rolling window: issue WINDOW chunks of loads before first consumption.
    Chunk win[WINDOW];
#pragma unroll
    for (int c = 0; c < WINDOW; ++c)
        load_chunk(win[c], nbr, mask, offs,
                   blockElemBase + (size_t)c * 4096 + (size_t)tid * 4);

    __syncthreads();   // positions ready (after load issue)

#pragma unroll
    for (int c = 0; c < CHUNKS; ++c) {
        const Chunk cur = win[c % WINDOW];

        // Refill the slot we just freed.
        if (c + WINDOW < CHUNKS)
            load_chunk(win[c % WINDOW], nbr, mask, offs,
                       blockElemBase + (size_t)(c + WINDOW) * 4096 +
                       (size_t)tid * 4);

        const int    eLocal = c * 4096 + tid * 4;
        const size_t e0     = blockElemBase + eLocal;
        const int    n      = nbase + (eLocal >> 7);   // row (K=128)
        const fx4    pi     = spos[n];

        const float ox[4] = {cur.o0.x, cur.o0.w, cur.o1.z, cur.o2.y};
        const float oy[4] = {cur.o0.y, cur.o1.x, cur.o1.w, cur.o2.z};
        const float oz[4] = {cur.o0.z, cur.o1.y, cur.o2.x, cur.o2.w};
        const int   j [4] = {cur.jj.x, cur.jj.y, cur.jj.z, cur.jj.w};
        const float m [4] = {cur.mm.x, cur.mm.y, cur.mm.z, cur.mm.w};

        float res[4];
#pragma unroll
        for (int i = 0; i < 4; ++i) {
            const fx4 pj = spos[j[i]];                 // one ds_read_b128
            const float dx = (pj.x - pi.x) + ox[i] * c00 + oy[i] * c10 + oz[i] * c20;
            const float dy = (pj.y - pi.y) + ox[i] * c01 + oy[i] * c11 + oz[i] * c21;
            const float dz = (pj.z - pi.z) + ox[i] * c02 + oy[i] * c12 + oz[i] * c22;
            const float sq = dx * dx + dy * dy + dz * dz;
            res[i] = (m[i] > 0.0f) ? __builtin_amdgcn_sqrtf(sq) : 0.0f;
        }

        const fx4 r = {res[0], res[1], res[2], res[3]};
        *(fx4*)(out + e0) = r;   // regular (cached, write-back) store
    }
}

extern "C" void kernel_launch(void* const* d_in, const int* in_sizes, int n_in,
                              void* d_out, int out_size, void* d_ws, size_t ws_size,
                              hipStream_t stream) {
    const float* positions     = (const float*)d_in[0]; // [B,N,3]
    const int*   neighbors     = (const int*)  d_in[1]; // [B,N,K]
    const float* neighbor_mask = (const float*)d_in[2]; // [B,N,K]
    const float* cell          = (const float*)d_in[3]; // [B,3,3]
    const float* cell_offsets  = (const float*)d_in[4]; // [B,N,K,3]
    float*       out           = (float*)d_out;         // [B,N,K]

    const int blocks = B * (N / ROWS_PER_BLOCK);        // 16 * 32 = 512

    pairwise_dist_cached<<<blocks, THREADS, 0, stream>>>(
        positions, neighbors, neighbor_mask, cell, cell_offsets, out);
}

// Round 6
// 207.501 us; speedup vs baseline: 1.0256x; 1.0226x over previous
//
#include <hip/hip_runtime.h>
#include <math.h>

// Problem constants (fixed by the reference harness).
constexpr int B = 16;
constexpr int N = 4096;
constexpr int K = 128;

constexpr int ROWS_PER_BLOCK = 128;  // 128 rows x 128 K = 16384 elems/block
constexpr int THREADS = 1024;        // 16 elems/thread: 4 chunks of 4
constexpr int CHUNKS  = 4;
constexpr int WINDOW  = 2;           // rolling lookahead (partially sunk @64 VGPR)

// Native clang vector types — required by __builtin_nontemporal_*.
typedef float fx4 __attribute__((ext_vector_type(4)));
typedef int   ix4 __attribute__((ext_vector_type(4)));

// R10: byte-exact revert to the measured optimum (R5: 60.8-63.6us/dispatch).
// Closed experiment matrix (R4-R9): MLP depth 1->10 (incl. guaranteed LDS-DMA
// pipeline), occupancy 9->56%, NT policies. Duration pinned at ~61-63us
// whenever cache policy is right; all-cached (R9) and LDS-DMA (R8) regress
// ~20%. Surviving model: per-CU outstanding-miss cap x poisoned-cache
// latency bounds read service at ~2.75 TB/s for this 5:1 R:W mix; request
// queue (not wave depth) is the binder. NT on zero-reuse streams (nbr/mask/
// out) protects L1/L2 from thrash; offs stays cached so its three 48B-stride
// sibling loads reuse fetched lines.

struct Chunk {
    ix4 jj;
    fx4 mm, o0, o1, o2;
};

__device__ __forceinline__ void load_chunk(Chunk& c,
                                           const int*   __restrict__ nbr,
                                           const float* __restrict__ mask,
                                           const float* __restrict__ offs,
                                           size_t e0) {
    c.jj = __builtin_nontemporal_load((const ix4*)(nbr  + e0));
    c.mm = __builtin_nontemporal_load((const fx4*)(mask + e0));
    // CACHED loads (no NT): the three sibling 16B loads share 48B-stride
    // cache lines; L1/L2 reuse keeps the 100MB stream at 1x fetch.
    const fx4* __restrict__ p = (const fx4*)(offs + e0 * 3);
    c.o0 = p[0];
    c.o1 = p[1];
    c.o2 = p[2];
}

__global__ __launch_bounds__(THREADS, 8)
void pairwise_dist_tlp(const float* __restrict__ pos,
                       const int*   __restrict__ nbr,
                       const float* __restrict__ mask,
                       const float* __restrict__ cell,
                       const float* __restrict__ offs,
                       float*       __restrict__ out) {
    __shared__ fx4 spos[N];          // 64 KB

    const int tid   = threadIdx.x;
    const int b     = blockIdx.x >> 5;    // 32 blocks per batch
    const int rblk  = blockIdx.x & 31;
    const int nbase = rblk * ROWS_PER_BLOCK;

    // Stage the batch's full positions: 1024 threads x 12 consecutive floats
    // (3x float4), repacked as 4 padded float4 atoms each. Coalesced.
    {
        const fx4* __restrict__ pb4 = (const fx4*)(pos + (size_t)b * N * 3);
        const fx4 r0 = pb4[tid * 3 + 0];
        const fx4 r1 = pb4[tid * 3 + 1];
        const fx4 r2 = pb4[tid * 3 + 2];
        const int a0 = tid * 4;
        spos[a0 + 0] = (fx4){r0.x, r0.y, r0.z, 0.f};
        spos[a0 + 1] = (fx4){r0.w, r1.x, r1.y, 0.f};
        spos[a0 + 2] = (fx4){r1.z, r1.w, r2.x, 0.f};
        spos[a0 + 3] = (fx4){r2.y, r2.z, r2.w, 0.f};
    }

    // Cell matrix: uniform per block -> scalar (s_load) path.
    const float* __restrict__ cb = cell + b * 9;
    const float c00 = cb[0], c01 = cb[1], c02 = cb[2];
    const float c10 = cb[3], c11 = cb[4], c12 = cb[5];
    const float c20 = cb[6], c21 = cb[7], c22 = cb[8];

    const size_t blockElemBase = ((size_t)b * N + nbase) * K;

    // Rolling window: issue WINDOW chunks of loads before first consumption.
    Chunk win[WINDOW];
#pragma unroll
    for (int c = 0; c < WINDOW; ++c)
        load_chunk(win[c], nbr, mask, offs,
                   blockElemBase + (size_t)c * 4096 + (size_t)tid * 4);

    __syncthreads();   // positions ready (after load issue)

#pragma unroll
    for (int c = 0; c < CHUNKS; ++c) {
        const Chunk cur = win[c % WINDOW];

        // Refill the slot we just freed.
        if (c + WINDOW < CHUNKS)
            load_chunk(win[c % WINDOW], nbr, mask, offs,
                       blockElemBase + (size_t)(c + WINDOW) * 4096 +
                       (size_t)tid * 4);

        const int    eLocal = c * 4096 + tid * 4;
        const size_t e0     = blockElemBase + eLocal;
        const int    n      = nbase + (eLocal >> 7);   // row (K=128)
        const fx4    pi     = spos[n];

        const float ox[4] = {cur.o0.x, cur.o0.w, cur.o1.z, cur.o2.y};
        const float oy[4] = {cur.o0.y, cur.o1.x, cur.o1.w, cur.o2.z};
        const float oz[4] = {cur.o0.z, cur.o1.y, cur.o2.x, cur.o2.w};
        const int   j [4] = {cur.jj.x, cur.jj.y, cur.jj.z, cur.jj.w};
        const float m [4] = {cur.mm.x, cur.mm.y, cur.mm.z, cur.mm.w};

        float res[4];
#pragma unroll
        for (int i = 0; i < 4; ++i) {
            const fx4 pj = spos[j[i]];                 // one ds_read_b128
            const float dx = (pj.x - pi.x) + ox[i] * c00 + oy[i] * c10 + oz[i] * c20;
            const float dy = (pj.y - pi.y) + ox[i] * c01 + oy[i] * c11 + oz[i] * c21;
            const float dz = (pj.z - pi.z) + ox[i] * c02 + oy[i] * c12 + oz[i] * c22;
            const float sq = dx * dx + dy * dy + dz * dz;
            res[i] = (m[i] > 0.0f) ? __builtin_amdgcn_sqrtf(sq) : 0.0f;
        }

        const fx4 r = {res[0], res[1], res[2], res[3]};
        __builtin_nontemporal_store(r, (fx4*)(out + e0));
    }
}

extern "C" void kernel_launch(void* const* d_in, const int* in_sizes, int n_in,
                              void* d_out, int out_size, void* d_ws, size_t ws_size,
                              hipStream_t stream) {
    const float* positions     = (const float*)d_in[0]; // [B,N,3]
    const int*   neighbors     = (const int*)  d_in[1]; // [B,N,K]
    const float* neighbor_mask = (const float*)d_in[2]; // [B,N,K]
    const float* cell          = (const float*)d_in[3]; // [B,3,3]
    const float* cell_offsets  = (const float*)d_in[4]; // [B,N,K,3]
    float*       out           = (float*)d_out;         // [B,N,K]

    const int blocks = B * (N / ROWS_PER_BLOCK);        // 16 * 32 = 512

    pairwise_dist_tlp<<<blocks, THREADS, 0, stream>>>(
        positions, neighbors, neighbor_mask, cell, cell_offsets, out);
}